// Round 8
// baseline (200.962 us; speedup 1.0000x reference)
//
#include <hip/hip_runtime.h>
#include <hip/hip_fp16.h>
#include <type_traits>

#define BATCH 2
#define SEQ 2048
#define EMB 1024
#define NH 16
#define HDIM 64

typedef _Float16 h16;
typedef __attribute__((ext_vector_type(8))) _Float16 h8;
typedef __attribute__((ext_vector_type(4))) _Float16 h4;
typedef __attribute__((ext_vector_type(4))) float f32x4;

#define MFMA16(a, b, c) __builtin_amdgcn_mfma_f32_16x16x32_f16((a), (b), (c), 0, 0, 0)
#define VMCNT0() asm volatile("s_waitcnt vmcnt(0)" ::: "memory")

// async global->LDS, 16B per lane. LDS dest is wave-uniform base + lane*16.
__device__ __forceinline__ void g2l16(const void* g, void* l) {
    __builtin_amdgcn_global_load_lds(
        (const __attribute__((address_space(1))) unsigned int*)g,
        (__attribute__((address_space(3))) unsigned int*)l, 16, 0, 0);
}

// ---------------------------------------------------------------------------
// x [B*S][E] f32 -> f16
__global__ __launch_bounds__(256) void k_cast_x(const float* __restrict__ x,
                                                h16* __restrict__ xh) {
    int i = (blockIdx.x * 256 + threadIdx.x) * 4;
    float4 v = *(const float4*)(x + i);
    h4 o = { (h16)v.x, (h16)v.y, (h16)v.z, (h16)v.w };
    *(h4*)(xh + i) = o;
}

// Wq/Wk/Wv [NH][EMB][HDIM] f32 -> wcat[(h*3+mat)*64+d][EMB] f16 (LDS-tiled, coalesced)
__global__ __launch_bounds__(256) void k_tr_qkv3(const float* __restrict__ wq,
                                                 const float* __restrict__ wk,
                                                 const float* __restrict__ wv,
                                                 h16* __restrict__ wcat) {
    __shared__ h16 ld[64][65];
    int g = blockIdx.x >> 4;
    int t = blockIdx.x & 15;
    int h = g / 3, mat = g - h * 3;
    const float* src = (mat == 0) ? wq : (mat == 1) ? wk : wv;
    int e0 = t * 64;
    int c0 = threadIdx.x & 63, r0 = threadIdx.x >> 6;
#pragma unroll
    for (int i = 0; i < 16; i++) {
        int e = i * 4 + r0;
        ld[c0][e] = (h16)src[((size_t)((h << 10) | (e0 + e))) * 64 + c0];
    }
    __syncthreads();
#pragma unroll
    for (int i = 0; i < 16; i++) {
        int d = i * 4 + r0;
        wcat[((size_t)(g * 64 + d) << 10) | (e0 + c0)] = ld[d][c0];
    }
}

// Wproj [PROJ_IN][EMB] f32 -> wpt [EMB_n][PROJ_IN_k] f16
__global__ __launch_bounds__(256) void k_tr_wp(const float* __restrict__ w,
                                               h16* __restrict__ wt) {
    __shared__ h16 ld[64][65];
    int kt = blockIdx.x & 15, ntl = blockIdx.x >> 4;
    int c0 = threadIdx.x & 63, r0 = threadIdx.x >> 6;
#pragma unroll
    for (int i = 0; i < 16; i++) {
        int k = i * 4 + r0;
        ld[c0][k] = (h16)w[((size_t)(kt * 64 + k) << 10) | (ntl * 64 + c0)];
    }
    __syncthreads();
#pragma unroll
    for (int i = 0; i < 16; i++) {
        int n = i * 4 + r0;
        wt[((size_t)(ntl * 64 + n) << 10) | (kt * 64 + c0)] = ld[n][c0];
    }
}

// ---------------------------------------------------------------------------
// QKV GEMM: 128x128 tile, BK=32, double-buffered LDS (32KB), prefetch t+1
// before compute(t), ONE vmcnt(0)+s_barrier per K-step.
__global__ __launch_bounds__(256) void k_qkv(
    const h16* __restrict__ xh, const h16* __restrict__ wcat,
    h16* __restrict__ Q, h16* __restrict__ Kk, h16* __restrict__ Vt) {
    __shared__ h16 As[2][128 * 32];   // 8KB each
    __shared__ h16 Bs[2][128 * 32];
    int tid = threadIdx.x;
    int wave = tid >> 6, lane = tid & 63;
    int lr = lane & 15, lg = lane >> 4, l2 = lr & 3;
    int wr = wave >> 1, wc = wave & 1;
    int swz = (blockIdx.x & 7) * 96 + (blockIdx.x >> 3);   // 768 = 8*96 bijective
    int nt = swz % 24, mt = swz / 24;

    const char* Ab = (const char*)xh + (size_t)mt * 128 * 2048;
    const char* Bb = (const char*)wcat + (size_t)nt * 128 * 2048;
    int rl = lane >> 2, gc = lane & 3;   // 16 rows x 4 granules (BK=32 rows = 64B)

    auto stage = [&](int buf, int k0) {
        size_t kb = (size_t)k0 * 2;
#pragma unroll
        for (int cc = 0; cc < 2; cc++) {
            int rb = (wave * 2 + cc) * 16;
            int row = rb + rl;
            size_t off = (size_t)row * 2048 + ((size_t)((gc ^ (row & 3)) << 4)) + kb;
            g2l16(Ab + off, &As[buf][rb * 32]);
            g2l16(Bb + off, &Bs[buf][rb * 32]);
        }
    };

    f32x4 acc[4][4];
#pragma unroll
    for (int m = 0; m < 4; m++)
#pragma unroll
        for (int n = 0; n < 4; n++) acc[m][n] = (f32x4){0.f, 0.f, 0.f, 0.f};

    stage(0, 0);
    VMCNT0();
    __builtin_amdgcn_s_barrier();
    __builtin_amdgcn_sched_barrier(0);

    for (int t = 0; t < 32; ++t) {
        int cur = t & 1;
        if (t + 1 < 32) stage(cur ^ 1, (t + 1) * 32);
        h8 a[4], b[4];
#pragma unroll
        for (int m = 0; m < 4; m++)
            a[m] = *(const h8*)&As[cur][(wr * 64 + m * 16 + lr) * 32 + ((lg ^ l2) << 3)];
#pragma unroll
        for (int n = 0; n < 4; n++)
            b[n] = *(const h8*)&Bs[cur][(wc * 64 + n * 16 + lr) * 32 + ((lg ^ l2) << 3)];
#pragma unroll
        for (int m = 0; m < 4; m++)
#pragma unroll
            for (int n = 0; n < 4; n++)
                acc[m][n] = MFMA16(a[m], b[n], acc[m][n]);
        VMCNT0();                         // this step's prefetch landed
        __builtin_amdgcn_s_barrier();     // all waves done reading buf[cur]
        __builtin_amdgcn_sched_barrier(0);
    }

    int g = nt * 2 + wc;
    int mat = g % 3, hh = g / 3;
    int row0 = mt * 128 + wr * 64;
    if (mat == 2) {
#pragma unroll
        for (int m = 0; m < 4; m++)
#pragma unroll
            for (int n = 0; n < 4; n++) {
                int row = row0 + m * 16 + lg * 4;
                int b = row >> 11, s = row & 2047;
                int bh = b * 16 + hh;
                int d = n * 16 + lr;
                h4 o = { (h16)acc[m][n][0], (h16)acc[m][n][1],
                         (h16)acc[m][n][2], (h16)acc[m][n][3] };
                *(h4*)&Vt[((size_t)bh * 64 + d) * 2048 + s] = o;
            }
    } else {
        h16* dst = mat ? Kk : Q;
        float qs = mat ? 1.0f : 0.18033688011112042f;   // 0.125*log2(e) for Q
#pragma unroll
        for (int m = 0; m < 4; m++)
#pragma unroll
            for (int n = 0; n < 4; n++)
#pragma unroll
                for (int r = 0; r < 4; r++) {
                    int row = row0 + m * 16 + lg * 4 + r;
                    int bh = (row >> 11) * 16 + hh, s = row & 2047;
                    dst[((size_t)bh * 2048 + s) * 64 + n * 16 + lr] =
                        (h16)(acc[m][n][r] * qs);
                }
    }
}

// ---------------------------------------------------------------------------
// Out-projection: 128x64 tile, BK=32, double-buffered (24KB), same schedule.
__global__ __launch_bounds__(256) void k_proj(
    const h16* __restrict__ att, const h16* __restrict__ wpt,
    const float* __restrict__ bias, float* __restrict__ out) {
    __shared__ h16 As[2][128 * 32];
    __shared__ h16 Bs[2][64 * 32];
    int tid = threadIdx.x;
    int wave = tid >> 6, lane = tid & 63;
    int lr = lane & 15, lg = lane >> 4, l2 = lr & 3;
    int swz = (blockIdx.x & 7) * 64 + (blockIdx.x >> 3);   // 512 = 8*64 bijective
    int nt = swz & 15, mt = swz >> 4;

    const char* Ab = (const char*)att + (size_t)mt * 128 * 2048;
    const char* Bb = (const char*)wpt + (size_t)nt * 64 * 2048;
    int rl = lane >> 2, gc = lane & 3;

    auto stage = [&](int buf, int k0) {
        size_t kb = (size_t)k0 * 2;
#pragma unroll
        for (int cc = 0; cc < 2; cc++) {
            int rb = (wave * 2 + cc) * 16;
            int row = rb + rl;
            size_t off = (size_t)row * 2048 + ((size_t)((gc ^ (row & 3)) << 4)) + kb;
            g2l16(Ab + off, &As[buf][rb * 32]);
        }
        int rbB = wave * 16;
        int rowB = rbB + rl;
        size_t offB = (size_t)rowB * 2048 + ((size_t)((gc ^ (rowB & 3)) << 4)) + kb;
        g2l16(Bb + offB, &Bs[buf][rbB * 32]);
    };

    f32x4 acc[2][4];
#pragma unroll
    for (int m = 0; m < 2; m++)
#pragma unroll
        for (int n = 0; n < 4; n++) acc[m][n] = (f32x4){0.f, 0.f, 0.f, 0.f};

    stage(0, 0);
    VMCNT0();
    __builtin_amdgcn_s_barrier();
    __builtin_amdgcn_sched_barrier(0);

    for (int t = 0; t < 32; ++t) {
        int cur = t & 1;
        if (t + 1 < 32) stage(cur ^ 1, (t + 1) * 32);
        h8 a[2], b[4];
#pragma unroll
        for (int m = 0; m < 2; m++)
            a[m] = *(const h8*)&As[cur][(wave * 32 + m * 16 + lr) * 32 + ((lg ^ l2) << 3)];
#pragma unroll
        for (int n = 0; n < 4; n++)
            b[n] = *(const h8*)&Bs[cur][(n * 16 + lr) * 32 + ((lg ^ l2) << 3)];
#pragma unroll
        for (int m = 0; m < 2; m++)
#pragma unroll
            for (int n = 0; n < 4; n++)
                acc[m][n] = MFMA16(a[m], b[n], acc[m][n]);
        VMCNT0();
        __builtin_amdgcn_s_barrier();
        __builtin_amdgcn_sched_barrier(0);
    }

#pragma unroll
    for (int m = 0; m < 2; m++)
#pragma unroll
        for (int n = 0; n < 4; n++)
#pragma unroll
            for (int r = 0; r < 4; r++) {
                int row = mt * 128 + wave * 32 + m * 16 + lg * 4 + r;
                int col = nt * 64 + n * 16 + lr;
                out[(size_t)row * 1024 + col] = acc[m][n][r] + bias[col];
            }
}

// ---------------------------------------------------------------------------
// Paired-chunk LDS-staged flash attention.
// Block = 4 waves; each wave owns 16 q-rows of chunk hi=(31-c) AND 16 of
// chunk lo=c -> every block does exactly 33 tile-computations (tail-free).
// K/V 64-tiles double-buffered (32KB), shared va frags for both chunks,
// ONE barrier per tile. Dual softmax chains per wave = ILP. Grid 512.
__device__ __forceinline__ void stage_kv(h16* Kb, h16* Vb,
                                         const h16* Kp, const h16* Vp,
                                         int ks0, int wave, int lane) {
    int rl = lane >> 3, gc = lane & 7;
    int sg = gc ^ rl;
#pragma unroll
    for (int c8 = 0; c8 < 2; c8++) {
        int rb = wave * 16 + c8 * 8;
        int row = rb + rl;
        g2l16((const char*)Kp + ((size_t)(ks0 + row) << 7) + (sg << 4), Kb + rb * 64);
        g2l16((const char*)Vp + ((size_t)row << 12) + ((size_t)ks0 << 1) + (sg << 4), Vb + rb * 64);
    }
}

__global__ __launch_bounds__(256, 2) void k_attn(
    const h16* __restrict__ Q, const h16* __restrict__ Kk,
    const h16* __restrict__ Vt, h16* __restrict__ att) {
    __shared__ h16 Kb[2][64 * 64];      // 16 KB
    __shared__ h16 Vb[2][64 * 64];      // 16 KB
    __shared__ h16 lp[4][2][16][64];    // 16 KB: (wave, chunk, q, k) XOR-swizzled

    int i = blockIdx.x;
    int x = i & 7, rest = i >> 3;
    int bh = x + ((rest & 3) << 3);     // XCD x -> 4 bh (K/V L2-local)
    int c = rest >> 2;                  // 0..15
    int b = bh >> 4, h = bh & 15;
    int wave = threadIdx.x >> 6, lane = threadIdx.x & 63;
    int lr = lane & 15, lg = lane >> 4, lx = lr & 7;
    int q0h = (31 - c) * 64 + wave * 16;
    int q0l = c * 64 + wave * 16;

    const h16* Qp = Q + (size_t)bh * SEQ * HDIM;
    const h16* Kp = Kk + (size_t)bh * SEQ * HDIM;
    const h16* Vp = Vt + (size_t)bh * HDIM * SEQ;

    // Q as B-operand (col=q, k-dim=d); pre-scaled by 0.125*log2e in k_qkv
    h8 qh_[2], ql_[2];
#pragma unroll
    for (int dc = 0; dc < 2; dc++) {
        qh_[dc] = *(const h8*)(Qp + (size_t)(q0h + lr) * 64 + dc * 32 + lg * 8);
        ql_[dc] = *(const h8*)(Qp + (size_t)(q0l + lr) * 64 + dc * 32 + lg * 8);
    }

    stage_kv(Kb[0], Vb[0], Kp, Vp, 0, wave, lane);
    VMCNT0();
    __builtin_amdgcn_s_barrier();
    __builtin_amdgcn_sched_barrier(0);

    float mxh = 0.f, mxl = 0.f, lsh = 0.f, lsl = 0.f;
    f32x4 oth[4], otl[4];
#pragma unroll
    for (int df = 0; df < 4; df++) {
        oth[df] = (f32x4){0.f, 0.f, 0.f, 0.f};
        otl[df] = (f32x4){0.f, 0.f, 0.f, 0.f};
    }

    int nkt = 32 - c;
    for (int kt = 0; kt < nkt; ++kt) {
        int ks0 = kt << 6;
        int cur = kt & 1;
        if (kt + 1 < nkt)
            stage_kv(Kb[cur ^ 1], Vb[cur ^ 1], Kp, Vp, (kt + 1) << 6, wave, lane);
        const h16* Kc = Kb[cur];
        const h16* Vc = Vb[cur];

        auto body = [&](auto LOC) {
            constexpr bool LO = decltype(LOC)::value;
            // ---- S^T = K @ Q^T for both chunks (shared K frags)
            f32x4 sh[4], sl[4];
#pragma unroll
            for (int kf = 0; kf < 4; kf++) {
                sh[kf] = (f32x4){0.f, 0.f, 0.f, 0.f};
                sl[kf] = (f32x4){0.f, 0.f, 0.f, 0.f};
            }
#pragma unroll
            for (int dc = 0; dc < 2; dc++) {
                h8 ka[4];
#pragma unroll
                for (int kf = 0; kf < 4; kf++)
                    ka[kf] = *(const h8*)&Kc[(kf * 16 + lr) * 64 + (((dc * 4 + lg) ^ lx) << 3)];
#pragma unroll
                for (int kf = 0; kf < 4; kf++) {
                    sh[kf] = MFMA16(ka[kf], qh_[dc], sh[kf]);
                    if constexpr (LO) sl[kf] = MFMA16(ka[kf], ql_[dc], sl[kf]);
                }
            }
            // ---- V frags (shared by both chunks)
            h8 va[2][4];
#pragma unroll
            for (int kc = 0; kc < 2; kc++)
#pragma unroll
                for (int df = 0; df < 4; df++)
                    va[kc][df] = *(const h8*)&Vc[(df * 16 + lr) * 64 + (((kc * 4 + lg) ^ lx) << 3)];
            // ---- causal masks (block-uniform last tiles)
            if (kt == nkt - 1) {
                int qg = q0h + lr;
#pragma unroll
                for (int kf = 0; kf < 4; kf++)
#pragma unroll
                    for (int r = 0; r < 4; r++)
                        if (ks0 + kf * 16 + lg * 4 + r > qg) sh[kf][r] = -1e30f;
            }
            if constexpr (LO) {
                if (kt == c) {
                    int qg = q0l + lr;
#pragma unroll
                    for (int kf = 0; kf < 4; kf++)
#pragma unroll
                        for (int r = 0; r < 4; r++)
                            if (ks0 + kf * 16 + lg * 4 + r > qg) sl[kf][r] = -1e30f;
                }
            }
            // ---- tile maxes (both chains independent)
            float tmh = sh[0][0], tml = 0.f;
#pragma unroll
            for (int kf = 0; kf < 4; kf++)
#pragma unroll
                for (int r = 0; r < 4; r++) tmh = fmaxf(tmh, sh[kf][r]);
            tmh = fmaxf(tmh, __shfl_xor(tmh, 16));
            tmh = fmaxf(tmh, __shfl_xor(tmh, 32));
            if constexpr (LO) {
                tml = sl[0][0];
#pragma unroll
                for (int kf = 0; kf < 4; kf++)
#pragma unroll
                    for (int r = 0; r < 4; r++) tml = fmaxf(tml, sl[kf][r]);
                tml = fmaxf(tml, __shfl_xor(tml, 16));
                tml = fmaxf(tml, __shfl_xor(tml, 32));
            }
            // ---- defer-max THR=8
            bool need = (tmh > mxh + 8.f);
            if constexpr (LO) need = need || (tml > mxl + 8.f);
            if (__any(need)) {
                float mn = fmaxf(mxh, tmh);
                float corr = exp2f(mxh - mn);
                lsh *= corr;
#pragma unroll
                for (int df = 0; df < 4; df++) oth[df] *= corr;
                mxh = mn;
                if constexpr (LO) {
                    float mnl = fmaxf(mxl, tml);
                    float cl = exp2f(mxl - mnl);
                    lsl *= cl;
#pragma unroll
                    for (int df = 0; df < 4; df++) otl[df] *= cl;
                    mxl = mnl;
                }
            }
            // ---- P = exp2(s - m) -> XOR-swizzled LDS (h4 packs)
            float tsh = 0.f, tsl = 0.f;
#pragma unroll
            for (int kf = 0; kf < 4; kf++) {
                float a0 = exp2f(sh[kf][0] - mxh), a1 = exp2f(sh[kf][1] - mxh);
                float a2 = exp2f(sh[kf][2] - mxh), a3 = exp2f(sh[kf][3] - mxh);
                tsh += (a0 + a1) + (a2 + a3);
                h4 ph = { (h16)a0, (h16)a1, (h16)a2, (h16)a3 };
                *(h4*)&lp[wave][0][lr][(((kf * 2 + (lg >> 1)) ^ lx) << 3) + ((lg & 1) << 2)] = ph;
                if constexpr (LO) {
                    float b0 = exp2f(sl[kf][0] - mxl), b1 = exp2f(sl[kf][1] - mxl);
                    float b2 = exp2f(sl[kf][2] - mxl), b3 = exp2f(sl[kf][3] - mxl);
                    tsl += (b0 + b1) + (b2 + b3);
                    h4 pl = { (h16)b0, (h16)b1, (h16)b2, (h16)b3 };
                    *(h4*)&lp[wave][1][lr][(((kf * 2 + (lg >> 1)) ^ lx) << 3) + ((lg & 1) << 2)] = pl;
                }
            }
            tsh += __shfl_xor(tsh, 16);
            tsh += __shfl_xor(tsh, 32);
            lsh += tsh;
            if constexpr (LO) {
                tsl += __shfl_xor(tsl, 16);
                tsl += __shfl_xor(tsl, 32);
                lsl += tsl;
            }
            // ---- O^T += V^T @ P^T (va shared)
#pragma unroll
            for (int kc = 0; kc < 2; kc++) {
                h8 pbh = *(const h8*)&lp[wave][0][lr][(((kc * 4 + lg) ^ lx) << 3)];
#pragma unroll
                for (int df = 0; df < 4; df++)
                    oth[df] = MFMA16(va[kc][df], pbh, oth[df]);
                if constexpr (LO) {
                    h8 pbl = *(const h8*)&lp[wave][1][lr][(((kc * 4 + lg) ^ lx) << 3)];
#pragma unroll
                    for (int df = 0; df < 4; df++)
                        otl[df] = MFMA16(va[kc][df], pbl, otl[df]);
                }
            }
        };
        if (kt <= c) body(std::integral_constant<bool, true>{});
        else         body(std::integral_constant<bool, false>{});

        VMCNT0();                         // this tile's prefetch landed
        __builtin_amdgcn_s_barrier();     // all waves done reading buf[cur]
        __builtin_amdgcn_sched_barrier(0);
    }
    // ---- epilogue: both chunks
    {
        float rl2 = 1.f / lsh;
        int q = q0h + lr;
#pragma unroll
        for (int df = 0; df < 4; df++) {
            h4 o = { (h16)(oth[df][0] * rl2), (h16)(oth[df][1] * rl2),
                     (h16)(oth[df][2] * rl2), (h16)(oth[df][3] * rl2) };
            *(h4*)&att[((size_t)(b * SEQ + q)) * 1024 + h * 64 + df * 16 + lg * 4] = o;
        }
    }
    {
        float rl2 = 1.f / lsl;
        int q = q0l + lr;
#pragma unroll
        for (int df = 0; df < 4; df++) {
            h4 o = { (h16)(otl[df][0] * rl2), (h16)(otl[df][1] * rl2),
                     (h16)(otl[df][2] * rl2), (h16)(otl[df][3] * rl2) };
            *(h4*)&att[((size_t)(b * SEQ + q)) * 1024 + h * 64 + df * 16 + lg * 4] = o;
        }
    }
}

// ---------------------------------------------------------------------------
extern "C" void kernel_launch(void* const* d_in, const int* in_sizes, int n_in,
                              void* d_out, int out_size, void* d_ws, size_t ws_size,
                              hipStream_t stream) {
    const float* x = (const float*)d_in[0];
    const float* Wq = (const float*)d_in[1];
    const float* Wk = (const float*)d_in[2];
    const float* Wv = (const float*)d_in[3];
    const float* Wp = (const float*)d_in[4];
    const float* bp = (const float*)d_in[5];
    float* out = (float*)d_out;

    char* p = (char*)d_ws;
    h16* xh = (h16*)p;   p += (size_t)BATCH * SEQ * EMB * 2;
    h16* wcat = (h16*)p; p += (size_t)NH * 3 * HDIM * EMB * 2;
    h16* wpt = (h16*)p;  p += (size_t)EMB * EMB * 2;
    h16* Qb = (h16*)p;   p += (size_t)BATCH * NH * SEQ * HDIM * 2;
    h16* Kb = (h16*)p;   p += (size_t)BATCH * NH * SEQ * HDIM * 2;
    h16* Vb = (h16*)p;   p += (size_t)BATCH * NH * SEQ * HDIM * 2;
    h16* attb = (h16*)p;

    k_cast_x<<<(BATCH * SEQ * EMB) / 4 / 256, 256, 0, stream>>>(x, xh);
    k_tr_qkv3<<<48 * 16, 256, 0, stream>>>(Wq, Wk, Wv, wcat);
    k_tr_wp<<<16 * 16, 256, 0, stream>>>(Wp, wpt);
    k_qkv<<<32 * 24, 256, 0, stream>>>(xh, wcat, Qb, Kb, Vb);
    k_attn<<<512, 256, 0, stream>>>(Qb, Kb, Vb, attb);
    k_proj<<<32 * 16, 256, 0, stream>>>(attb, wpt, bp, out);
}

// Round 10
// 196.676 us; speedup vs baseline: 1.0218x; 1.0218x over previous
//
#include <hip/hip_runtime.h>
#include <hip/hip_fp16.h>
#include <type_traits>

#define BATCH 2
#define SEQ 2048
#define EMB 1024
#define NH 16
#define HDIM 64

typedef _Float16 h16;
typedef __attribute__((ext_vector_type(8))) _Float16 h8;
typedef __attribute__((ext_vector_type(4))) _Float16 h4;
typedef __attribute__((ext_vector_type(4))) float f32x4;

#define MFMA16(a, b, c) __builtin_amdgcn_mfma_f32_16x16x32_f16((a), (b), (c), 0, 0, 0)
#define VMCNT0() asm volatile("s_waitcnt vmcnt(0)" ::: "memory")

// async global->LDS, 16B per lane. LDS dest is wave-uniform base + lane*16.
__device__ __forceinline__ void g2l16(const void* g, void* l) {
    __builtin_amdgcn_global_load_lds(
        (const __attribute__((address_space(1))) unsigned int*)g,
        (__attribute__((address_space(3))) unsigned int*)l, 16, 0, 0);
}

// ---------------------------------------------------------------------------
// x [B*S][E] f32 -> f16
__global__ __launch_bounds__(256) void k_cast_x(const float* __restrict__ x,
                                                h16* __restrict__ xh) {
    int i = (blockIdx.x * 256 + threadIdx.x) * 4;
    float4 v = *(const float4*)(x + i);
    h4 o = { (h16)v.x, (h16)v.y, (h16)v.z, (h16)v.w };
    *(h4*)(xh + i) = o;
}

// Wq/Wk/Wv [NH][EMB][HDIM] f32 -> wcat[(h*3+mat)*64+d][EMB] f16 (LDS-tiled, coalesced)
__global__ __launch_bounds__(256) void k_tr_qkv3(const float* __restrict__ wq,
                                                 const float* __restrict__ wk,
                                                 const float* __restrict__ wv,
                                                 h16* __restrict__ wcat) {
    __shared__ h16 ld[64][65];
    int g = blockIdx.x >> 4;
    int t = blockIdx.x & 15;
    int h = g / 3, mat = g - h * 3;
    const float* src = (mat == 0) ? wq : (mat == 1) ? wk : wv;
    int e0 = t * 64;
    int c0 = threadIdx.x & 63, r0 = threadIdx.x >> 6;
#pragma unroll
    for (int i = 0; i < 16; i++) {
        int e = i * 4 + r0;
        ld[c0][e] = (h16)src[((size_t)((h << 10) | (e0 + e))) * 64 + c0];
    }
    __syncthreads();
#pragma unroll
    for (int i = 0; i < 16; i++) {
        int d = i * 4 + r0;
        wcat[((size_t)(g * 64 + d) << 10) | (e0 + c0)] = ld[d][c0];
    }
}

// Wproj [PROJ_IN][EMB] f32 -> wpt [EMB_n][PROJ_IN_k] f16
__global__ __launch_bounds__(256) void k_tr_wp(const float* __restrict__ w,
                                               h16* __restrict__ wt) {
    __shared__ h16 ld[64][65];
    int kt = blockIdx.x & 15, ntl = blockIdx.x >> 4;
    int c0 = threadIdx.x & 63, r0 = threadIdx.x >> 6;
#pragma unroll
    for (int i = 0; i < 16; i++) {
        int k = i * 4 + r0;
        ld[c0][k] = (h16)w[((size_t)(kt * 64 + k) << 10) | (ntl * 64 + c0)];
    }
    __syncthreads();
#pragma unroll
    for (int i = 0; i < 16; i++) {
        int n = i * 4 + r0;
        wt[((size_t)(ntl * 64 + n) << 10) | (kt * 64 + c0)] = ld[n][c0];
    }
}

// ---------------------------------------------------------------------------
// QKV GEMM (round-7 measured-best): 128x128 tile, BK=64, single-buffered.
__global__ __launch_bounds__(256) void k_qkv(
    const h16* __restrict__ xh, const h16* __restrict__ wcat,
    h16* __restrict__ Q, h16* __restrict__ Kk, h16* __restrict__ Vt) {
    __shared__ h16 As[128 * 64];   // 16KB
    __shared__ h16 Bs[128 * 64];   // 16KB
    int tid = threadIdx.x;
    int wave = tid >> 6, lane = tid & 63;
    int lr = lane & 15, lg = lane >> 4, lx = lr & 7;
    int wr = wave >> 1, wc = wave & 1;
    int swz = (blockIdx.x & 7) * 96 + (blockIdx.x >> 3);   // 768 = 8*96 bijective
    int nt = swz % 24, mt = swz / 24;

    const char* Ab = (const char*)xh + (size_t)mt * 128 * 2048;
    const char* Bb = (const char*)wcat + (size_t)nt * 128 * 2048;
    int rl = lane >> 3, gc = lane & 7;
    size_t lofs = (size_t)rl * 2048 + ((gc ^ rl) << 4);

    f32x4 acc[4][4];
#pragma unroll
    for (int m = 0; m < 4; m++)
#pragma unroll
        for (int n = 0; n < 4; n++) acc[m][n] = (f32x4){0.f, 0.f, 0.f, 0.f};

    for (int k0 = 0; k0 < 1024; k0 += 64) {
        size_t kb = (size_t)k0 * 2;
#pragma unroll
        for (int c = 0; c < 4; c++) {
            int rb = c * 32 + wave * 8;
            g2l16(Ab + (size_t)rb * 2048 + lofs + kb, As + rb * 64);
            g2l16(Bb + (size_t)rb * 2048 + lofs + kb, Bs + rb * 64);
        }
        __syncthreads();
#pragma unroll
        for (int dc = 0; dc < 2; dc++) {
            h8 a[4], b[4];
#pragma unroll
            for (int m = 0; m < 4; m++)
                a[m] = *(const h8*)&As[(wr * 64 + m * 16 + lr) * 64 + (((dc * 4 + lg) ^ lx) << 3)];
#pragma unroll
            for (int n = 0; n < 4; n++)
                b[n] = *(const h8*)&Bs[(wc * 64 + n * 16 + lr) * 64 + (((dc * 4 + lg) ^ lx) << 3)];
#pragma unroll
            for (int m = 0; m < 4; m++)
#pragma unroll
                for (int n = 0; n < 4; n++)
                    acc[m][n] = MFMA16(a[m], b[n], acc[m][n]);
        }
        __syncthreads();
    }

    int g = nt * 2 + wc;
    int mat = g % 3, hh = g / 3;
    int row0 = mt * 128 + wr * 64;
    if (mat == 2) {
#pragma unroll
        for (int m = 0; m < 4; m++)
#pragma unroll
            for (int n = 0; n < 4; n++) {
                int row = row0 + m * 16 + lg * 4;
                int b = row >> 11, s = row & 2047;
                int bh = b * 16 + hh;
                int d = n * 16 + lr;
                h4 o = { (h16)acc[m][n][0], (h16)acc[m][n][1],
                         (h16)acc[m][n][2], (h16)acc[m][n][3] };
                *(h4*)&Vt[((size_t)bh * 64 + d) * 2048 + s] = o;
            }
    } else {
        h16* dst = mat ? Kk : Q;
        float qs = mat ? 1.0f : 0.18033688011112042f;   // 0.125*log2(e) for Q
#pragma unroll
        for (int m = 0; m < 4; m++)
#pragma unroll
            for (int n = 0; n < 4; n++)
#pragma unroll
                for (int r = 0; r < 4; r++) {
                    int row = row0 + m * 16 + lg * 4 + r;
                    int bh = (row >> 11) * 16 + hh, s = row & 2047;
                    dst[((size_t)bh * 2048 + s) * 64 + n * 16 + lr] =
                        (h16)(acc[m][n][r] * qs);
                }
    }
}

// ---------------------------------------------------------------------------
// Out-projection (round-7 measured-best): 128x64 tile, BK=64, single-buffered.
__global__ __launch_bounds__(256) void k_proj(
    const h16* __restrict__ att, const h16* __restrict__ wpt,
    const float* __restrict__ bias, float* __restrict__ out) {
    __shared__ h16 As[128 * 64];   // 16KB
    __shared__ h16 Bs[64 * 64];    // 8KB
    int tid = threadIdx.x;
    int wave = tid >> 6, lane = tid & 63;
    int lr = lane & 15, lg = lane >> 4, lx = lr & 7;
    int swz = (blockIdx.x & 7) * 64 + (blockIdx.x >> 3);   // 512 = 8*64 bijective
    int nt = swz & 15, mt = swz >> 4;

    const char* Ab = (const char*)att + (size_t)mt * 128 * 2048;
    const char* Bb = (const char*)wpt + (size_t)nt * 64 * 2048;
    int rl = lane >> 3, gc = lane & 7;
    size_t lofs = (size_t)rl * 2048 + ((gc ^ rl) << 4);

    f32x4 acc[2][4];
#pragma unroll
    for (int m = 0; m < 2; m++)
#pragma unroll
        for (int n = 0; n < 4; n++) acc[m][n] = (f32x4){0.f, 0.f, 0.f, 0.f};

    for (int k0 = 0; k0 < 1024; k0 += 64) {
        size_t kb = (size_t)k0 * 2;
#pragma unroll
        for (int c = 0; c < 4; c++) {
            int rb = c * 32 + wave * 8;
            g2l16(Ab + (size_t)rb * 2048 + lofs + kb, As + rb * 64);
            if (c < 2)
                g2l16(Bb + (size_t)rb * 2048 + lofs + kb, Bs + rb * 64);
        }
        __syncthreads();
#pragma unroll
        for (int dc = 0; dc < 2; dc++) {
            h8 a[2], b[4];
#pragma unroll
            for (int m = 0; m < 2; m++)
                a[m] = *(const h8*)&As[(wave * 32 + m * 16 + lr) * 64 + (((dc * 4 + lg) ^ lx) << 3)];
#pragma unroll
            for (int n = 0; n < 4; n++)
                b[n] = *(const h8*)&Bs[(n * 16 + lr) * 64 + (((dc * 4 + lg) ^ lx) << 3)];
#pragma unroll
            for (int m = 0; m < 2; m++)
#pragma unroll
                for (int n = 0; n < 4; n++)
                    acc[m][n] = MFMA16(a[m], b[n], acc[m][n]);
        }
        __syncthreads();
    }

#pragma unroll
    for (int m = 0; m < 2; m++)
#pragma unroll
        for (int n = 0; n < 4; n++)
#pragma unroll
            for (int r = 0; r < 4; r++) {
                int row = mt * 128 + wave * 32 + m * 16 + lg * 4 + r;
                int col = nt * 64 + n * 16 + lr;
                out[(size_t)row * 1024 + col] = acc[m][n][r] + bias[col];
            }
}

// ---------------------------------------------------------------------------
// Split-K balanced flash attention (duration-equalized blocks).
// Pair chunk H=31-c with L=c. Block(bh,c,0): H, k-tiles [0,16) -> partial.
// Block(bh,c,1): H, k-tiles [16,32-c) -> partial; then L, [0,c] -> final.
// Every block = 16 or 17 tiles. Hi-chunk partials merged by k_merge.
// Grid 1024 = 4 blocks/CU (LDS 40KB), durations uniform -> occupancy holds.
__device__ __forceinline__ void stage_kv(h16* Kb, h16* Vb,
                                         const h16* Kp, const h16* Vp,
                                         int ks0, int wave, int lane) {
    int rl = lane >> 3, gc = lane & 7;
    int sg = gc ^ rl;
#pragma unroll
    for (int c8 = 0; c8 < 2; c8++) {
        int rb = wave * 16 + c8 * 8;
        int row = rb + rl;
        g2l16((const char*)Kp + ((size_t)(ks0 + row) << 7) + (sg << 4), Kb + rb * 64);
        g2l16((const char*)Vp + ((size_t)row << 12) + ((size_t)ks0 << 1) + (sg << 4), Vb + rb * 64);
    }
}

__global__ __launch_bounds__(256, 4) void k_attn(
    const h16* __restrict__ Q, const h16* __restrict__ Kk,
    const h16* __restrict__ Vt, h16* __restrict__ att,
    float* __restrict__ O1, float* __restrict__ ml1,
    float* __restrict__ O2, float* __restrict__ ml2) {
    __shared__ h16 Kb[2][64 * 64];   // 16 KB
    __shared__ h16 Vb[2][64 * 64];   // 16 KB
    __shared__ h16 lp[4][16][64];    // 8 KB, XOR-swizzled per-wave P tile

    int i = blockIdx.x;
    int x = i & 7, rest = i >> 3;                 // XCD locality: bh%8==x
    int bh = x + ((rest & 3) << 3);
    int c = (rest >> 2) & 15;
    int half = rest >> 6;
    int b = bh >> 4, h = bh & 15;
    int wave = threadIdx.x >> 6, lane = threadIdx.x & 63;
    int lr = lane & 15, lg = lane >> 4, lx = lr & 7;

    const h16* Qp = Q + (size_t)bh * SEQ * HDIM;
    const h16* Kp = Kk + (size_t)bh * SEQ * HDIM;
    const h16* Vp = Vt + (size_t)bh * HDIM * SEQ;

    int H = 31 - c;

    // One chunk pass over k-tiles [kt0, kt1); diagTile gets the causal mask.
    auto pass = [&](int q0c, int kt0, int kt1, int diagTile, auto FINALC,
                    float* Op, float* mlp) {
        constexpr bool FINAL = decltype(FINALC)::value;
        int q0 = q0c + wave * 16;
        h8 qb[2];
#pragma unroll
        for (int dc = 0; dc < 2; dc++)
            qb[dc] = *(const h8*)(Qp + (size_t)(q0 + lr) * 64 + dc * 32 + lg * 8);

        float mx = 0.f, lsum = 0.f;
        f32x4 ot[4];
#pragma unroll
        for (int df = 0; df < 4; df++) ot[df] = (f32x4){0.f, 0.f, 0.f, 0.f};

        stage_kv(Kb[0], Vb[0], Kp, Vp, kt0 << 6, wave, lane);
        VMCNT0();
        __builtin_amdgcn_s_barrier();
        __builtin_amdgcn_sched_barrier(0);

        for (int kt = kt0; kt < kt1; ++kt) {
            int ks0 = kt << 6;
            int cur = (kt - kt0) & 1;
            if (kt + 1 < kt1)
                stage_kv(Kb[cur ^ 1], Vb[cur ^ 1], Kp, Vp, (kt + 1) << 6, wave, lane);
            const h16* Kc = Kb[cur];
            const h16* Vc = Vb[cur];
            // ---- S^T = K @ Q^T
            f32x4 st[4];
#pragma unroll
            for (int kf = 0; kf < 4; kf++) st[kf] = (f32x4){0.f, 0.f, 0.f, 0.f};
#pragma unroll
            for (int dc = 0; dc < 2; dc++) {
                h8 ka[4];
#pragma unroll
                for (int kf = 0; kf < 4; kf++)
                    ka[kf] = *(const h8*)&Kc[(kf * 16 + lr) * 64 + (((dc * 4 + lg) ^ lx) << 3)];
#pragma unroll
                for (int kf = 0; kf < 4; kf++)
                    st[kf] = MFMA16(ka[kf], qb[dc], st[kf]);
            }
            // ---- V frags
            h8 va[2][4];
#pragma unroll
            for (int kc = 0; kc < 2; kc++)
#pragma unroll
                for (int df = 0; df < 4; df++)
                    va[kc][df] = *(const h8*)&Vc[(df * 16 + lr) * 64 + (((kc * 4 + lg) ^ lx) << 3)];
            // ---- causal mask (diag tile only; block-uniform)
            if (kt == diagTile) {
                int qg = q0 + lr;
#pragma unroll
                for (int kf = 0; kf < 4; kf++)
#pragma unroll
                    for (int r = 0; r < 4; r++)
                        if (ks0 + kf * 16 + lg * 4 + r > qg) st[kf][r] = -1e30f;
            }
            // ---- tile max: depth-4 tree (max3-fusable) + 2 shfls
            float t0 = fmaxf(fmaxf(st[0][0], st[0][1]), fmaxf(st[0][2], st[0][3]));
            float t1 = fmaxf(fmaxf(st[1][0], st[1][1]), fmaxf(st[1][2], st[1][3]));
            float t2 = fmaxf(fmaxf(st[2][0], st[2][1]), fmaxf(st[2][2], st[2][3]));
            float t3 = fmaxf(fmaxf(st[3][0], st[3][1]), fmaxf(st[3][2], st[3][3]));
            float tm = fmaxf(fmaxf(t0, t1), fmaxf(t2, t3));
            tm = fmaxf(tm, __shfl_xor(tm, 16));
            tm = fmaxf(tm, __shfl_xor(tm, 32));
            // ---- defer-max THR=8
            if (__any(tm > mx + 8.f)) {
                float mn = fmaxf(mx, tm);
                float corr = exp2f(mx - mn);
                lsum *= corr;
#pragma unroll
                for (int df = 0; df < 4; df++) ot[df] *= corr;
                mx = mn;
            }
            // ---- P = exp2(st - m) -> XOR-swizzled LDS
            float ts = 0.f;
#pragma unroll
            for (int kf = 0; kf < 4; kf++) {
                float p0 = exp2f(st[kf][0] - mx);
                float p1 = exp2f(st[kf][1] - mx);
                float p2 = exp2f(st[kf][2] - mx);
                float p3 = exp2f(st[kf][3] - mx);
                ts += (p0 + p1) + (p2 + p3);
                h4 ph = { (h16)p0, (h16)p1, (h16)p2, (h16)p3 };
                *(h4*)&lp[wave][lr][(((kf * 2 + (lg >> 1)) ^ lx) << 3) + ((lg & 1) << 2)] = ph;
            }
            ts += __shfl_xor(ts, 16);
            ts += __shfl_xor(ts, 32);
            lsum += ts;
            // ---- O^T += V^T @ P^T
#pragma unroll
            for (int kc = 0; kc < 2; kc++) {
                h8 pb = *(const h8*)&lp[wave][lr][(((kc * 4 + lg) ^ lx) << 3)];
#pragma unroll
                for (int df = 0; df < 4; df++)
                    ot[df] = MFMA16(va[kc][df], pb, ot[df]);
            }
            VMCNT0();
            __builtin_amdgcn_s_barrier();
            __builtin_amdgcn_sched_barrier(0);
        }
        // ---- epilogue
        int q = q0 + lr;
        if constexpr (FINAL) {
            float rl2 = 1.f / lsum;
#pragma unroll
            for (int df = 0; df < 4; df++) {
                h4 o = { (h16)(ot[df][0] * rl2), (h16)(ot[df][1] * rl2),
                         (h16)(ot[df][2] * rl2), (h16)(ot[df][3] * rl2) };
                *(h4*)&att[((size_t)(b * SEQ + q)) * 1024 + h * 64 + df * 16 + lg * 4] = o;
            }
        } else {
            size_t r = ((size_t)bh << 10) + (q - 1024);   // hi rows only
            float* Ob = Op + r * 64;
#pragma unroll
            for (int df = 0; df < 4; df++)
                *(f32x4*)&Ob[df * 16 + lg * 4] = ot[df];
            if (lg == 0) {
                mlp[r * 2] = mx;
                mlp[r * 2 + 1] = lsum;
            }
        }
    };

    if (half == 0) {
        // H-chunk, first 16 k-tiles (never touches the diagonal: H >= 16)
        pass(H * 64, 0, 16, H, std::integral_constant<bool, false>{}, O1, ml1);
    } else {
        // H-chunk, remaining tiles (diag at kt=H), partial
        pass(H * 64, 16, H + 1, H, std::integral_constant<bool, false>{}, O2, ml2);
        // L-chunk complete (diag at kt=c), final
        pass(c * 64, 0, c + 1, c, std::integral_constant<bool, true>{}, nullptr, nullptr);
    }
}

// ---------------------------------------------------------------------------
// Merge the two hi-chunk partials: att = (w1*O1 + w2*O2) / (w1*l1 + w2*l2).
__global__ __launch_bounds__(256) void k_merge(
    const float* __restrict__ O1, const float* __restrict__ ml1,
    const float* __restrict__ O2, const float* __restrict__ ml2,
    h16* __restrict__ att) {
    int t = blockIdx.x * 256 + threadIdx.x;   // over 32*1024*64
    int d = t & 63;
    int r = t >> 6;                           // bh*1024 + (q-1024)
    int bh = r >> 10, qh = r & 1023;
    float m1 = ml1[r * 2], l1 = ml1[r * 2 + 1];
    float m2 = ml2[r * 2], l2 = ml2[r * 2 + 1];
    float m = fmaxf(m1, m2);
    float w1 = exp2f(m1 - m), w2 = exp2f(m2 - m);
    float o = w1 * O1[t] + w2 * O2[t];
    float l = w1 * l1 + w2 * l2;
    int b = bh >> 4, h = bh & 15;
    att[((size_t)(b * SEQ + 1024 + qh)) * 1024 + h * 64 + d] = (h16)(o / l);
}

// ---------------------------------------------------------------------------
extern "C" void kernel_launch(void* const* d_in, const int* in_sizes, int n_in,
                              void* d_out, int out_size, void* d_ws, size_t ws_size,
                              hipStream_t stream) {
    const float* x = (const float*)d_in[0];
    const float* Wq = (const float*)d_in[1];
    const float* Wk = (const float*)d_in[2];
    const float* Wv = (const float*)d_in[3];
    const float* Wp = (const float*)d_in[4];
    const float* bp = (const float*)d_in[5];
    float* out = (float*)d_out;

    char* p = (char*)d_ws;
    h16* xh = (h16*)p;   p += (size_t)BATCH * SEQ * EMB * 2;          // 8 MB
    h16* wcat = (h16*)p; p += (size_t)NH * 3 * HDIM * EMB * 2;        // 6 MB
    h16* wpt = (h16*)p;  p += (size_t)EMB * EMB * 2;                  // 2 MB
    h16* Qb = (h16*)p;   p += (size_t)BATCH * NH * SEQ * HDIM * 2;    // 8 MB
    h16* Kb = (h16*)p;   p += (size_t)BATCH * NH * SEQ * HDIM * 2;    // 8 MB
    h16* Vb = (h16*)p;   p += (size_t)BATCH * NH * SEQ * HDIM * 2;    // 8 MB
    h16* attb = (h16*)p; p += (size_t)BATCH * SEQ * EMB * 2;          // 8 MB
    float* O1 = (float*)p;  p += (size_t)32 * 1024 * 64 * 4;          // 8.4 MB
    float* O2 = (float*)p;  p += (size_t)32 * 1024 * 64 * 4;          // 8.4 MB
    float* ml1 = (float*)p; p += (size_t)32 * 1024 * 2 * 4;           // 256 KB
    float* ml2 = (float*)p;                                           // 256 KB

    k_cast_x<<<(BATCH * SEQ * EMB) / 4 / 256, 256, 0, stream>>>(x, xh);
    k_tr_qkv3<<<48 * 16, 256, 0, stream>>>(Wq, Wk, Wv, wcat);
    k_tr_wp<<<16 * 16, 256, 0, stream>>>(Wp, wpt);
    k_qkv<<<32 * 24, 256, 0, stream>>>(xh, wcat, Qb, Kb, Vb);
    k_attn<<<1024, 256, 0, stream>>>(Qb, Kb, Vb, attb, O1, ml1, O2, ml2);
    k_merge<<<(32 * 1024 * 64) / 256, 256, 0, stream>>>(O1, ml1, O2, ml2, attb);
    k_proj<<<32 * 16, 256, 0, stream>>>(attb, wpt, bp, out);
}